// Round 19
// baseline (230.813 us; speedup 1.0000x reference)
//
#include <hip/hip_runtime.h>

// out[e,i] = sum_j mat[e,i,j] v[e,j] + bias[e,i],  [mat|bias] = MLP(pos).reshape(32,33)
// Round-20: split tuning #2. r18: g_pass stuck at 2 waves/SIMD (AGPR total >170,
// per-wave B regs), h2_pass LDS-capped at 2 blocks/CU. Fixes:
//  (1) g_pass: B via block-shared LDS double-buffer (r4 global_load_lds, 1 bar/chunk)
//      -> no per-wave bf regs, 4x less L2 B-traffic; (256,3) + LDS 50704 -> 3 w/SIMD.
//  (2) h2_pass: drop W2L (B-frags from L2), w1r 4-col slices -> LDS 34816 (4 blk/CU),
//      arch ~60 <= 85 -> true 3 waves/SIMD.
//   P[e, col] = h2[e,0:128] @ Wpack[0:128, col]   (col = j*32+i; W3-only)
//   out[e,i]  = sum_{col: i} vext[e,j] * P[e,col] + (b3 mini-GEMM C-init)
// ws: Wg2 @0 (270336), W2f @270336 (32768), b3f @303104 (2048), b3c @305152 (128),
//     h2frag @524288 (67108864). NEED = 67633152 B. Fallback = r13 fused (98.7us).
// h2frag layout: fragment group G=e0/16, ks: [(G*4+ks)*512 + lane*8 + jj] =
//   h2[G*16 + (lane&15)][ks*32 + (lane>>4)*8 + jj]  (= af[m][ks] load, 16B/lane).

#define E_TOTAL 262144
#define EPB 256
#define NBLK (E_TOTAL / EPB)
#define NEED_WS (524288ull + 67108864ull)

typedef float f32x4 __attribute__((ext_vector_type(4)));
typedef short s8v  __attribute__((ext_vector_type(8)));
typedef short s4v  __attribute__((ext_vector_type(4)));
typedef unsigned int u32;

__device__ __forceinline__ unsigned short f2bf(float x) {
  unsigned u = __float_as_uint(x);
  u += 0x7fffu + ((u >> 16) & 1u);
  return (unsigned short)(u >> 16);
}

__device__ __forceinline__ void ld16_g2l(const void* g, void* l) {
  __builtin_amdgcn_global_load_lds((const __attribute__((address_space(1))) u32*)g,
                                   (__attribute__((address_space(3))) u32*)l, 16, 0, 0);
}

// ---------------- prep: pack W2/W3/b3 into MFMA B-fragment order ----------------
__global__ void prep_pack(const float* __restrict__ W2, const float* __restrict__ W3,
                          const float* __restrict__ b3,
                          unsigned short* __restrict__ Wg2, unsigned short* __restrict__ W2f,
                          unsigned short* __restrict__ b3f, float* __restrict__ b3c) {
  int idx = blockIdx.x * 256 + threadIdx.x;   // 528 blocks cover 135168
  if (idx < 135168) {
    int k = idx / 1056, c = idx % 1056;
    int i = c / 33, jc = c % 33;
    int col = jc * 32 + i;                    // Wg2 col = j*32 + i
    int nnt = col >> 4, low = col & 15;
    int nn = (nnt & 1) ? (33 + (nnt >> 1)) : (nnt >> 1);   // permuted tile order
    int ks = k >> 5, kr = k & 31;
    int lane = ((kr >> 3) << 4) + low;
    int jj = k & 7;
    Wg2[((nn * 4 + ks) * 64 + lane) * 8 + jj] = f2bf(W3[idx]);
  }
  if (idx < 16384) {
    int k = idx >> 7, n = idx & 127;
    int ks = k >> 5, kr = k & 31;
    int nt = n >> 4, low = n & 15;
    int l = ((kr >> 3) << 4) + low;
    int jj = k & 7;
    W2f[((ks * 8 + nt) * 64 + l) * 8 + jj] = f2bf(W2[idx]);
  }
  if (idx < 1024) {
    int jj = idx & 7, lane = (idx >> 3) & 63, ih = idx >> 9;
    int j = ((lane >> 4) << 3) + jj, i = ih * 16 + (lane & 15);
    b3f[idx] = f2bf(b3[i * 33 + j]);
  }
  if (idx < 32) b3c[idx] = b3[idx * 33 + 32];
}

// ---------------- h2_pass: MLP stages 1+2, 256 edges/block -> h2frag ----------------
// 1024 blocks x 256 threads (4 waves). LDS 34816 (4 blk/CU); arch ~60 -> (256,3).
__global__ __launch_bounds__(256, 3) void h2_pass(
    const float* __restrict__ pos_i, const float* __restrict__ pos_j,
    const float* __restrict__ W1, const float* __restrict__ b1,
    const float* __restrict__ b2, const unsigned short* __restrict__ W2f,
    unsigned short* __restrict__ h2frag) {
  __shared__ __attribute__((aligned(16))) char smem[34816];
  unsigned short* h1c = (unsigned short*)smem;               // [64][136]
  unsigned short* h2n = (unsigned short*)(smem + 17408);     // [64][136]

  const int tid = threadIdx.x;
  const int w = tid >> 6, lane = tid & 63, q = lane >> 4, ln = lane & 15;
  const int B0 = blockIdx.x * EPB;

  // W1/b1 slice: 4 cols/thread (20 regs); b2 slice (8 regs)
  const int hh0 = (tid & 31) * 4;
  float w1r[4][4], b1r4[4], b2r[8];
#pragma unroll
  for (int d = 0; d < 4; ++d)
#pragma unroll
    for (int u = 0; u < 4; ++u) w1r[d][u] = W1[d * 128 + hh0 + u];
#pragma unroll
  for (int u = 0; u < 4; ++u) b1r4[u] = b1[hh0 + u];
#pragma unroll
  for (int s = 0; s < 8; ++s) b2r[s] = b2[s * 16 + ln];

  for (int qtr = 0; qtr < 4; ++qtr) {
    // stage 1: 64 edges x 128 cols; thread (tid>>5)+half*8 x cols hh0..hh0+3
#pragma unroll
    for (int half = 0; half < 8; ++half) {
      int ee = (tid >> 5) + half * 8;
      int eg = B0 + qtr * 64 + ee;
      float2 pi = *(const float2*)(pos_i + (size_t)eg * 2);
      float2 pj = *(const float2*)(pos_j + (size_t)eg * 2);
      s4v hv;
#pragma unroll
      for (int u = 0; u < 4; ++u) {
        float o = b1r4[u] + pi.x * w1r[0][u] + pi.y * w1r[1][u] +
                  pj.x * w1r[2][u] + pj.y * w1r[3][u];
        hv[u] = (short)f2bf(fmaxf(o, 0.f));
      }
      *(s4v*)&h1c[ee * 136 + hh0] = hv;
    }
    __syncthreads();   // h1c ready

    // stage 2: wave w owns edges [w*16, w*16+16), iterates 8 nt; B-frags from L2
#pragma unroll
    for (int s = 0; s < 8; ++s) {
      f32x4 a4 = {0.f, 0.f, 0.f, 0.f};
#pragma unroll
      for (int ks = 0; ks < 4; ++ks) {
        s8v afr = *(const s8v*)&h1c[(w * 16 + ln) * 136 + ks * 32 + q * 8];
        s8v bfr = *(const s8v*)(W2f + ((ks * 8 + s) * 64 + lane) * 8);
        a4 = __builtin_amdgcn_mfma_f32_16x16x32_bf16(afr, bfr, a4, 0, 0, 0);
      }
      int eb = w * 16 + q * 4;
      int kc = s * 16 + ln;
#pragma unroll
      for (int r = 0; r < 4; ++r)
        h2n[(eb + r) * 136 + kc] = f2bf(fmaxf(a4[r] + b2r[s], 0.f));
    }
    __syncthreads();   // h2n ready (all 64 edges of this qtr)

    // copy-out in MFMA-fragment order: thread t -> fragment f=t>>4, sub-lane s=t&15
    // (next qtr's h2n writes are fenced by its own post-stage-1 barrier)
    {
      int f = tid >> 4, g = f >> 2, ks = f & 3, s = tid & 15;
      unsigned short* dst =
          h2frag + ((size_t)(blockIdx.x * 16 + qtr * 4 + g) * 4 + ks) * 512;
#pragma unroll
      for (int r4 = 0; r4 < 4; ++r4) {
        int l = s * 4 + r4;
        s8v v = *(const s8v*)&h2n[(g * 16 + (l & 15)) * 136 + ks * 32 + (l >> 4) * 8];
        *(s8v*)&dst[l * 8] = v;
      }
    }
  }
}

// ---------------- g_pass helpers ----------------
// LDS-buffered B; oa is the CURRENT ih half only (r7 ih-split); m-outer single-p
__device__ __forceinline__ void tile_computeL(const unsigned short* __restrict__ buf, int t,
                                              const float* __restrict__ vt, int j,
                                              int lane, int eoff,
                                              const s8v (&af)[4][4], float (&oa)[4][4]) {
  const f32x4 zero4 = {0.f, 0.f, 0.f, 0.f};
  s8v bfr[4];
#pragma unroll
  for (int ks = 0; ks < 4; ++ks)
    bfr[ks] = *(const s8v*)&buf[(t * 4 + ks) * 512 + lane * 8];
  const float* vp = vt + j * 260 + eoff;
#pragma unroll
  for (int m = 0; m < 4; ++m) {
    f32x4 vv = *(const f32x4*)(vp + m * 16);
    f32x4 p = __builtin_amdgcn_mfma_f32_16x16x32_bf16(af[m][0], bfr[0], zero4, 0, 0, 0);
#pragma unroll
    for (int ks = 1; ks < 4; ++ks)
      p = __builtin_amdgcn_mfma_f32_16x16x32_bf16(af[m][ks], bfr[ks], p, 0, 0, 0);
#pragma unroll
    for (int r = 0; r < 4; ++r) oa[m][r] += vv[r] * p[r];
  }
}

__device__ __forceinline__ void init_oa(float (&oa)[4][4], const float* __restrict__ vj,
                                        const unsigned short* __restrict__ b3f,
                                        const float* __restrict__ b3c,
                                        int B0, int w, int q, int ln, int lane, int ih) {
  s8v b3fr = *(const s8v*)(b3f + (ih * 64 + lane) * 8);
  float cbv = b3c[ih * 16 + ln];
  f32x4 ci = {cbv, cbv, cbv, cbv};
#pragma unroll
  for (int m = 0; m < 4; ++m) {
    int e = B0 + w * 64 + m * 16 + ln;
    const float4 va = *(const float4*)(vj + (size_t)e * 32 + q * 8);
    const float4 vb = *(const float4*)(vj + (size_t)e * 32 + q * 8 + 4);
    s8v t;
    t[0] = (short)f2bf(va.x); t[1] = (short)f2bf(va.y);
    t[2] = (short)f2bf(va.z); t[3] = (short)f2bf(va.w);
    t[4] = (short)f2bf(vb.x); t[5] = (short)f2bf(vb.y);
    t[6] = (short)f2bf(vb.z); t[7] = (short)f2bf(vb.w);
    f32x4 p = __builtin_amdgcn_mfma_f32_16x16x32_bf16(t, b3fr, ci, 0, 0, 0);
#pragma unroll
    for (int r = 0; r < 4; ++r) oa[m][r] = p[r];
  }
}

__device__ __forceinline__ void store_half(float* __restrict__ out, const float (&oa)[4][4],
                                           int B0, int w, int q, int ln, int ih) {
#pragma unroll
  for (int m = 0; m < 4; ++m)
#pragma unroll
    for (int r = 0; r < 4; ++r) {
      int e = B0 + w * 64 + m * 16 + q * 4 + r;
      out[(size_t)e * 32 + ih * 16 + ln] = oa[m][r];
    }
}

// ---------------- g_pass: einsum G-loop; af from h2frag; LDS-staged B ----------------
// 256 threads (4 waves), 256 edges/block. LDS: vt[33][260]@0 (34320) +
// Bb u16[2][4096]@34320 (16384) = 50704 -> 3 blocks/CU; (256,3) -> 3 waves/SIMD.
__global__ __launch_bounds__(256, 3) void g_pass(
    const float* __restrict__ vj, const unsigned short* __restrict__ Wg2,
    const unsigned short* __restrict__ b3f, const float* __restrict__ b3c,
    const unsigned short* __restrict__ h2frag, float* __restrict__ out) {
  __shared__ __attribute__((aligned(16))) char smem[50704];
  float* vt = (float*)smem;                                  // [33][260]
  unsigned short* Bb  = (unsigned short*)(smem + 34320);     // [2][4096]
  char* BbChar = smem + 34320;

  const int tid = threadIdx.x;
  const int w = tid >> 6, lane = tid & 63, q = lane >> 4, ln = lane & 15;
  const int B0 = blockIdx.x * EPB;
  const int eoff = w * 64 + q * 4;

  // prime chunk 0 (tiles 0,1) into Bb buffer 0
  {
    const unsigned short* src = Wg2 + tid * 8;
    char* dstb = BbChar + w * 1024;   // wave-uniform base
    ld16_g2l(src, dstb);
    ld16_g2l(src + 2048, dstb + 4096);
  }

  // af fragments from h2frag (coalesced 16B/lane)
  s8v af[4][4];
#pragma unroll
  for (int m = 0; m < 4; ++m)
#pragma unroll
    for (int ks = 0; ks < 4; ++ks)
      af[m][ks] = *(const s8v*)&h2frag[((size_t)(blockIdx.x * 16 + w * 4 + m) * 4 + ks) * 512 + lane * 8];

  // build vt: vt[j][e] = v[e,j], row 32 = 1.0
  {
    const float* vrow = vj + (size_t)(B0 + tid) * 32;
#pragma unroll
    for (int j4 = 0; j4 < 8; ++j4) {
      float4 vv = *(const float4*)(vrow + j4 * 4);
      vt[(j4 * 4 + 0) * 260 + tid] = vv.x;
      vt[(j4 * 4 + 1) * 260 + tid] = vv.y;
      vt[(j4 * 4 + 2) * 260 + tid] = vv.z;
      vt[(j4 * 4 + 3) * 260 + tid] = vv.w;
    }
    vt[32 * 260 + tid] = 1.0f;
  }

  // oa init for ih=0
  float oa[4][4];
  init_oa(oa, vj, b3f, b3c, B0, w, q, ln, lane, 0);
  __syncthreads();   // vt ready; barrier drain covers chunk-0 staging

  // G-loop: 33 chunks x 2 tiles, double-buffered async staging, 1 barrier/chunk
#pragma unroll 1
  for (int c = 0; c < 16; ++c) {        // tiles 0..31, output half ih=0
    const unsigned short* buf = Bb + (c & 1) * 4096;
    {
      const unsigned short* src = Wg2 + (size_t)(c + 1) * 4096 + tid * 8;
      char* dstb = BbChar + ((c + 1) & 1) * 8192 + w * 1024;
      ld16_g2l(src, dstb);
      ld16_g2l(src + 2048, dstb + 4096);
    }
    tile_computeL(buf, 0, vt, 2 * c,     lane, eoff, af, oa);
    tile_computeL(buf, 1, vt, 2 * c + 1, lane, eoff, af, oa);
    __syncthreads();
  }
  {                                     // straddle chunk 16: tile 32 (ih0,j=32), tile 33 (ih1,j=0)
    const unsigned short* buf = Bb;     // 16&1 == 0
    {
      const unsigned short* src = Wg2 + (size_t)17 * 4096 + tid * 8;
      char* dstb = BbChar + 8192 + w * 1024;
      ld16_g2l(src, dstb);
      ld16_g2l(src + 2048, dstb + 4096);
    }
    tile_computeL(buf, 0, vt, 32, lane, eoff, af, oa);
    store_half(out, oa, B0, w, q, ln, 0);                 // ih=0 complete
    init_oa(oa, vj, b3f, b3c, B0, w, q, ln, lane, 1);     // re-init for ih=1
    tile_computeL(buf, 1, vt, 0, lane, eoff, af, oa);
    __syncthreads();
  }
#pragma unroll 1
  for (int c = 17; c < 33; ++c) {       // tiles 34..65, output half ih=1; j = 2c-33, 2c-32
    const unsigned short* buf = Bb + (c & 1) * 4096;
    if (c < 32) {
      const unsigned short* src = Wg2 + (size_t)(c + 1) * 4096 + tid * 8;
      char* dstb = BbChar + ((c + 1) & 1) * 8192 + w * 1024;
      ld16_g2l(src, dstb);
      ld16_g2l(src + 2048, dstb + 4096);
    }
    tile_computeL(buf, 0, vt, 2 * c - 33, lane, eoff, af, oa);
    tile_computeL(buf, 1, vt, 2 * c - 32, lane, eoff, af, oa);
    __syncthreads();
  }
  store_half(out, oa, B0, w, q, ln, 1);
}

// ---------------- FALLBACK: r13 fused kernel (98.7us proven), if ws too small ----
__device__ __forceinline__ void tile_load(s8v (&dst)[4], const unsigned short* __restrict__ Wg2,
                                          int n, int lane) {
  const s8v* src = (const s8v*)(Wg2 + (size_t)n * 2048 + lane * 8);
#pragma unroll
  for (int ks = 0; ks < 4; ++ks) dst[ks] = src[ks * 64];
}

template <int IH>
__device__ __forceinline__ void tile_compute2(const s8v (&bf)[4], const float* __restrict__ vt,
                                              int j, int eoff,
                                              const s8v (&af)[4][4], float (&oa)[2][4][4]) {
  const f32x4 zero4 = {0.f, 0.f, 0.f, 0.f};
  const float* vp = vt + j * 260 + eoff;
#pragma unroll
  for (int m = 0; m < 4; ++m) {
    f32x4 p = __builtin_amdgcn_mfma_f32_16x16x32_bf16(af[m][0], bf[0], zero4, 0, 0, 0);
#pragma unroll
    for (int ks = 1; ks < 4; ++ks)
      p = __builtin_amdgcn_mfma_f32_16x16x32_bf16(af[m][ks], bf[ks], p, 0, 0, 0);
    f32x4 vv = *(const f32x4*)(vp + m * 16);
#pragma unroll
    for (int r = 0; r < 4; ++r) oa[IH][m][r] += vv[r] * p[r];
  }
}

__global__ __launch_bounds__(256, 2) void fnn_fused(
    const float* __restrict__ pos_i, const float* __restrict__ pos_j,
    const float* __restrict__ vj, const float* __restrict__ W1,
    const float* __restrict__ b1, const float* __restrict__ b2,
    const unsigned short* __restrict__ W2f, const unsigned short* __restrict__ Wg2,
    const unsigned short* __restrict__ b3f, const float* __restrict__ b3c,
    float* __restrict__ out) {
  __shared__ __attribute__((aligned(16))) char smem[67584];
  float* vt = (float*)smem;
  unsigned short* h1c = (unsigned short*)smem;
  unsigned short* h2n = (unsigned short*)(smem + 17408);
  unsigned short* W2L = (unsigned short*)(smem + 34816);

  const int tid = threadIdx.x;
  const int w = tid >> 6, lane = tid & 63, q = lane >> 4, ln = lane & 15;
  const int B0 = blockIdx.x * EPB;
  const int eoff = w * 64 + q * 4;

  {
    const unsigned short* src = W2f + tid * 8;
    char* dstb = smem + 34816 + w * 1024;
#pragma unroll
    for (int cc = 0; cc < 8; ++cc)
      ld16_g2l(src + cc * 2048, dstb + cc * 4096);
  }

  float oa[2][4][4];
  {
    s8v av[4];
#pragma unroll
    for (int m = 0; m < 4; ++m) {
      int e = B0 + w * 64 + m * 16 + ln;
      const float4 va = *(const float4*)(vj + (size_t)e * 32 + q * 8);
      const float4 vb = *(const float4*)(vj + (size_t)e * 32 + q * 8 + 4);
      s8v t;
      t[0] = (short)f2bf(va.x); t[1] = (short)f2bf(va.y);
      t[2] = (short)f2bf(va.z); t[3] = (short)f2bf(va.w);
      t[4] = (short)f2bf(vb.x); t[5] = (short)f2bf(vb.y);
      t[6] = (short)f2bf(vb.z); t[7] = (short)f2bf(vb.w);
      av[m] = t;
    }
#pragma unroll
    for (int ih = 0; ih < 2; ++ih) {
      s8v b3fr = *(const s8v*)(b3f + (ih * 64 + lane) * 8);
      float cbv = b3c[ih * 16 + ln];
      f32x4 ci = {cbv, cbv, cbv, cbv};
#pragma unroll
      for (int m = 0; m < 4; ++m) {
        f32x4 p = __builtin_amdgcn_mfma_f32_16x16x32_bf16(av[m], b3fr, ci, 0, 0, 0);
#pragma unroll
        for (int r = 0; r < 4; ++r) oa[ih][m][r] = p[r];
      }
    }
  }

  const int hh0 = (tid & 15) * 8;
  float w1r[4][8], b1r[8], b2r[8];
#pragma unroll
  for (int d = 0; d < 4; ++d)
#pragma unroll
    for (int u = 0; u < 8; ++u) w1r[d][u] = W1[d * 128 + hh0 + u];
#pragma unroll
  for (int u = 0; u < 8; ++u) b1r[u] = b1[hh0 + u];
#pragma unroll
  for (int s = 0; s < 8; ++s) b2r[s] = b2[s * 16 + ln];

  s8v af[4][4];
  for (int qtr = 0; qtr < 4; ++qtr) {
#pragma unroll
    for (int half = 0; half < 4; ++half) {
      int ee = (tid >> 4) + half * 16;
      int eg = B0 + qtr * 64 + ee;
      float2 pi = *(const float2*)(pos_i + (size_t)eg * 2);
      float2 pj = *(const float2*)(pos_j + (size_t)eg * 2);
      s8v hv;
#pragma unroll
      for (int u = 0; u < 8; ++u) {
        float o = b1r[u] + pi.x * w1r[0][u] + pi.y * w1r[1][u] +
                  pj.x * w1r[2][u] + pj.y * w1r[3][u];
        hv[u] = (short)f2bf(fmaxf(o, 0.f));
      }
      *(s8v*)&h1c[ee * 136 + hh0] = hv;
    }
    __syncthreads();
#pragma unroll
    for (int s = 0; s < 8; ++s) {
      f32x4 a4 = {0.f, 0.f, 0.f, 0.f};
#pragma unroll
      for (int ks = 0; ks < 4; ++ks) {
        s8v afr = *(const s8v*)&h1c[(w * 16 + ln) * 136 + ks * 32 + q * 8];
        s8v bfr = *(const s8v*)&W2L[((ks * 8 + s) * 64 + lane) * 8];
        a4 = __builtin_amdgcn_mfma_f32_16x16x32_bf16(afr, bfr, a4, 0, 0, 0);
      }
      int eb = w * 16 + q * 4;
      int kc = s * 16 + ln;
#pragma unroll
      for (int r = 0; r < 4; ++r)
        h2n[(eb + r) * 136 + kc] = f2bf(fmaxf(a4[r] + b2r[s], 0.f));
    }
    __syncthreads();
    if (w == qtr) {
#pragma unroll
      for (int m = 0; m < 4; ++m)
#pragma unroll
        for (int ks = 0; ks < 4; ++ks)
          af[m][ks] = *(const s8v*)&h2n[(m * 16 + ln) * 136 + ks * 32 + q * 8];
    }
    __syncthreads();
  }

  s8v bf[4];
  tile_load(bf, Wg2, 0, lane);

  {
    const float* vrow = vj + (size_t)(B0 + tid) * 32;
#pragma unroll
    for (int j4 = 0; j4 < 8; ++j4) {
      float4 vv = *(const float4*)(vrow + j4 * 4);
      vt[(j4 * 4 + 0) * 260 + tid] = vv.x;
      vt[(j4 * 4 + 1) * 260 + tid] = vv.y;
      vt[(j4 * 4 + 2) * 260 + tid] = vv.z;
      vt[(j4 * 4 + 3) * 260 + tid] = vv.w;
    }
    vt[32 * 260 + tid] = 1.0f;
  }

#pragma unroll 1
  for (int n = 0; n < 33; ++n) {
    tile_compute2<0>(bf, vt, n, eoff, af, oa);
    tile_load(bf, Wg2, n + 1, lane);
  }
#pragma unroll 1
  for (int n = 33; n < 66; ++n) {
    tile_compute2<1>(bf, vt, n - 33, eoff, af, oa);
    tile_load(bf, Wg2, n + 1, lane);
  }

#pragma unroll
  for (int m = 0; m < 4; ++m)
#pragma unroll
    for (int ih = 0; ih < 2; ++ih)
#pragma unroll
      for (int r = 0; r < 4; ++r) {
        int e = B0 + w * 64 + m * 16 + q * 4 + r;
        out[(size_t)e * 32 + ih * 16 + ln] = oa[ih][m][r];
      }
}

extern "C" void kernel_launch(void* const* d_in, const int* in_sizes, int n_in,
                              void* d_out, int out_size, void* d_ws, size_t ws_size,
                              hipStream_t stream) {
  const float* pos_i = (const float*)d_in[0];
  const float* pos_j = (const float*)d_in[1];
  const float* vj    = (const float*)d_in[2];
  const float* W1    = (const float*)d_in[3];
  const float* b1    = (const float*)d_in[4];
  const float* W2    = (const float*)d_in[5];
  const float* b2    = (const float*)d_in[6];
  const float* W3    = (const float*)d_in[7];
  const float* b3    = (const float*)d_in[8];
  float* outp = (float*)d_out;

  unsigned short* Wg2 = (unsigned short*)d_ws;
  unsigned short* W2f = (unsigned short*)((char*)d_ws + 270336);
  unsigned short* b3f = (unsigned short*)((char*)d_ws + 303104);
  float*          b3c = (float*)((char*)d_ws + 305152);
  unsigned short* h2frag = (unsigned short*)((char*)d_ws + 524288);

  prep_pack<<<528, 256, 0, stream>>>(W2, W3, b3, Wg2, W2f, b3f, b3c);
  if (ws_size >= NEED_WS) {
    h2_pass<<<NBLK, 256, 0, stream>>>(pos_i, pos_j, W1, b1, b2, W2f, h2frag);
    g_pass<<<NBLK, 256, 0, stream>>>(vj, Wg2, b3f, b3c, h2frag, outp);
  } else {
    fnn_fused<<<NBLK, 256, 0, stream>>>(pos_i, pos_j, vj, W1, b1, b2, W2f, Wg2, b3f, b3c, outp);
  }
}

// Round 20
// 197.038 us; speedup vs baseline: 1.1714x; 1.1714x over previous
//
#include <hip/hip_runtime.h>

// out[e,i] = sum_j mat[e,i,j] v[e,j] + bias[e,i],  [mat|bias] = MLP(pos).reshape(32,33)
// Round-21: REVERT to r13 (best measured: 98.7us kernel, 177.5us bench; fused,
// W2L LDS-staged prologue, 9 barriers, barrier-free reg-B G-loop, (256,2), zero
// spill) + ONE bounded tweak: s_setprio(1) around the G-loop MFMA chains (T5).
// Mechanism: post-prologue waves free-run (no barriers) at ~2-3 waves/SIMD,
// alternating MFMA-chain and VALU-epilogue phases — the attn-like regime where
// setprio measured +4-7% (m191), unlike lockstep GEMM (m190 null). Prologue
// untouched (barrier-synced lockstep).
// Split-kernel arc (r17-r19) closed: h2_pass+g_pass >= 111us > 98.7 fused; the
// h2frag 67MB round-trip + g_pass's unfixable 2.4 waves/SIMD eat the gains.
//   P[e, col] = h2[e,0:128] @ Wpack[0:128, col]   (col = j*32+i; W3-only)
//   out[e,i]  = sum_{col: i} vext[e,j] * P[e,col] + (b3 mini-GEMM)
// LDS 67584 B (prologue: h1c[64][136] @0, h2n[64][136] @17408, W2L @34816;
// G-loop: vt[33][260] @0 overlays h1c+h2n). 2 blocks/CU (reg-capped anyway).
// ws: Wg2 @0 (270336), W2f @270336 (32768), b3f @303104 (2048), b3c @305152 (128).

#define E_TOTAL 262144
#define EPB 256
#define NBLK (E_TOTAL / EPB)

typedef float f32x4 __attribute__((ext_vector_type(4)));
typedef short s8v  __attribute__((ext_vector_type(8)));
typedef unsigned int u32;

__device__ __forceinline__ unsigned short f2bf(float x) {
  unsigned u = __float_as_uint(x);
  u += 0x7fffu + ((u >> 16) & 1u);
  return (unsigned short)(u >> 16);
}

__device__ __forceinline__ void ld16_g2l(const void* g, void* l) {
  __builtin_amdgcn_global_load_lds((const __attribute__((address_space(1))) u32*)g,
                                   (__attribute__((address_space(3))) u32*)l, 16, 0, 0);
}

// ---------------- prep: pack W2/W3/b3 into MFMA B-fragment order ----------------
// Coalesced f32 reads, scattered bf16 writes (r7 version, verified).
__global__ void prep_pack(const float* __restrict__ W2, const float* __restrict__ W3,
                          const float* __restrict__ b3,
                          unsigned short* __restrict__ Wg2, unsigned short* __restrict__ W2f,
                          unsigned short* __restrict__ b3f, float* __restrict__ b3c) {
  int idx = blockIdx.x * 256 + threadIdx.x;   // 528 blocks cover 135168
  if (idx < 135168) {
    int k = idx / 1056, c = idx % 1056;
    int i = c / 33, jc = c % 33;
    int col = jc * 32 + i;                    // Wg2 col = j*32 + i
    int nnt = col >> 4, low = col & 15;
    int nn = (nnt & 1) ? (33 + (nnt >> 1)) : (nnt >> 1);   // permuted tile order
    int ks = k >> 5, kr = k & 31;
    int lane = ((kr >> 3) << 4) + low;
    int jj = k & 7;
    Wg2[((nn * 4 + ks) * 64 + lane) * 8 + jj] = f2bf(W3[idx]);
  }
  if (idx < 16384) {
    int k = idx >> 7, n = idx & 127;
    int ks = k >> 5, kr = k & 31;
    int nt = n >> 4, low = n & 15;
    int l = ((kr >> 3) << 4) + low;
    int jj = k & 7;
    W2f[((ks * 8 + nt) * 64 + l) * 8 + jj] = f2bf(W2[idx]);
  }
  if (idx < 1024) {
    int jj = idx & 7, lane = (idx >> 3) & 63, ih = idx >> 9;
    int j = ((lane >> 4) << 3) + jj, i = ih * 16 + (lane & 15);
    b3f[idx] = f2bf(b3[i * 33 + j]);
  }
  if (idx < 32) b3c[idx] = b3[idx * 33 + 32];
}

// ---------------- G-loop helpers (register-resident B, direct from L2) ----------------
__device__ __forceinline__ void tile_load(s8v (&dst)[4], const unsigned short* __restrict__ Wg2,
                                          int n, int lane) {
  const s8v* src = (const s8v*)(Wg2 + (size_t)n * 2048 + lane * 8);
#pragma unroll
  for (int ks = 0; ks < 4; ++ks) dst[ks] = src[ks * 64];
}

template <int IH>
__device__ __forceinline__ void tile_compute(const s8v (&bf)[4], const float* __restrict__ vt,
                                             int j, int eoff,
                                             const s8v (&af)[4][4], float (&oa)[2][4][4]) {
  const f32x4 zero4 = {0.f, 0.f, 0.f, 0.f};
  const float* vp = vt + j * 260 + eoff;
#pragma unroll
  for (int m = 0; m < 4; ++m) {
    __builtin_amdgcn_s_setprio(1);   // favor the MFMA chain over co-resident waves'
    f32x4 p = __builtin_amdgcn_mfma_f32_16x16x32_bf16(af[m][0], bf[0], zero4, 0, 0, 0);
#pragma unroll
    for (int ks = 1; ks < 4; ++ks)
      p = __builtin_amdgcn_mfma_f32_16x16x32_bf16(af[m][ks], bf[ks], p, 0, 0, 0);
    __builtin_amdgcn_s_setprio(0);   // epilogue FMA/loads at normal priority
    f32x4 vv = *(const f32x4*)(vp + m * 16);
#pragma unroll
    for (int r = 0; r < 4; ++r) oa[IH][m][r] += vv[r] * p[r];
  }
}

// ---------------- fused main kernel (r13 structure) ----------------
// 256 threads (4 waves), 256 edges/block; wave w owns edges [B0+w*64, B0+w*64+64).
// LDS: prologue h1c u16[64][136] @0, h2n u16[64][136] @17408, W2L u16[16384] @34816;
//      G-loop vt f32[33][260] @0 (overlays h1c+h2n). Total 67584 B.
__global__ __launch_bounds__(256, 2) void fnn_fused(
    const float* __restrict__ pos_i, const float* __restrict__ pos_j,
    const float* __restrict__ vj, const float* __restrict__ W1,
    const float* __restrict__ b1, const float* __restrict__ b2,
    const unsigned short* __restrict__ W2f, const unsigned short* __restrict__ Wg2,
    const unsigned short* __restrict__ b3f, const float* __restrict__ b3c,
    float* __restrict__ out) {
  __shared__ __attribute__((aligned(16))) char smem[67584];
  float* vt = (float*)smem;                                  // [33][260], G-loop phase
  unsigned short* h1c = (unsigned short*)smem;               // [64][136], prologue
  unsigned short* h2n = (unsigned short*)(smem + 17408);     // [64][136], prologue
  unsigned short* W2L = (unsigned short*)(smem + 34816);     // [16384],   prologue

  const int tid = threadIdx.x;
  const int w = tid >> 6, lane = tid & 63, q = lane >> 4, ln = lane & 15;
  const int B0 = blockIdx.x * EPB;
  const int eoff = w * 64 + q * 4;

  // --- stage W2f -> LDS once (async, zero registers; drained by first barrier) ---
  {
    const unsigned short* src = W2f + tid * 8;
    char* dstb = smem + 34816 + w * 1024;   // wave-uniform base
#pragma unroll
    for (int cc = 0; cc < 8; ++cc)
      ld16_g2l(src + cc * 2048, dstb + cc * 4096);
  }

  // --- out-acc init via b3 mini-GEMM: oa[ih][m][r] = sum_j v[e,j] b3[i*33+j] + b3[i*33+32] ---
  float oa[2][4][4];
  {
    s8v av[4];
#pragma unroll
    for (int m = 0; m < 4; ++m) {
      int e = B0 + w * 64 + m * 16 + ln;
      const float4 va = *(const float4*)(vj + (size_t)e * 32 + q * 8);
      const float4 vb = *(const float4*)(vj + (size_t)e * 32 + q * 8 + 4);
      s8v t;
      t[0] = (short)f2bf(va.x); t[1] = (short)f2bf(va.y);
      t[2] = (short)f2bf(va.z); t[3] = (short)f2bf(va.w);
      t[4] = (short)f2bf(vb.x); t[5] = (short)f2bf(vb.y);
      t[6] = (short)f2bf(vb.z); t[7] = (short)f2bf(vb.w);
      av[m] = t;
    }
#pragma unroll
    for (int ih = 0; ih < 2; ++ih) {
      s8v b3fr = *(const s8v*)(b3f + (ih * 64 + lane) * 8);
      float cbv = b3c[ih * 16 + ln];
      f32x4 ci = {cbv, cbv, cbv, cbv};
#pragma unroll
      for (int m = 0; m < 4; ++m) {
        f32x4 p = __builtin_amdgcn_mfma_f32_16x16x32_bf16(av[m], b3fr, ci, 0, 0, 0);
#pragma unroll
        for (int r = 0; r < 4; ++r) oa[ih][m][r] = p[r];
      }
    }
  }

  // --- W1/b1/b2 register slices ---
  const int hh0 = (tid & 15) * 8;
  float w1r[4][8], b1r[8], b2r[8];
#pragma unroll
  for (int d = 0; d < 4; ++d)
#pragma unroll
    for (int u = 0; u < 8; ++u) w1r[d][u] = W1[d * 128 + hh0 + u];
#pragma unroll
  for (int u = 0; u < 8; ++u) b1r[u] = b1[hh0 + u];
#pragma unroll
  for (int s = 0; s < 8; ++s) b2r[s] = b2[s * 16 + ln];

  // --- stages 1+2 per quarter (64 edges/phase), 2 barriers/qtr ---
  s8v af[4][4];
  for (int qtr = 0; qtr < 4; ++qtr) {
    // stage 1: all 64 edges of this quarter; thread computes 4 edges x 8 cols
#pragma unroll
    for (int half = 0; half < 4; ++half) {
      int ee = (tid >> 4) + half * 16;
      int eg = B0 + qtr * 64 + ee;
      float2 pi = *(const float2*)(pos_i + (size_t)eg * 2);
      float2 pj = *(const float2*)(pos_j + (size_t)eg * 2);
      s8v hv;
#pragma unroll
      for (int u = 0; u < 8; ++u) {
        float o = b1r[u] + pi.x * w1r[0][u] + pi.y * w1r[1][u] +
                  pj.x * w1r[2][u] + pj.y * w1r[3][u];
        hv[u] = (short)f2bf(fmaxf(o, 0.f));
      }
      *(s8v*)&h1c[ee * 136 + hh0] = hv;
    }
    __syncthreads();   // h1c ready (also drains W2L staging on qtr 0)

    // stage 2: wave w owns tile-row mt=w (edges w*16..w*16+16), iterates 8 nt
#pragma unroll
    for (int s = 0; s < 8; ++s) {
      f32x4 a4 = {0.f, 0.f, 0.f, 0.f};
#pragma unroll
      for (int ks = 0; ks < 4; ++ks) {
        s8v afr = *(const s8v*)&h1c[(w * 16 + ln) * 136 + ks * 32 + q * 8];
        s8v bfr = *(const s8v*)&W2L[((ks * 8 + s) * 64 + lane) * 8];
        a4 = __builtin_amdgcn_mfma_f32_16x16x32_bf16(afr, bfr, a4, 0, 0, 0);
      }
      int eb = w * 16 + q * 4;
      int kc = s * 16 + ln;
#pragma unroll
      for (int r = 0; r < 4; ++r)
        h2n[(eb + r) * 136 + kc] = f2bf(fmaxf(a4[r] + b2r[s], 0.f));
    }
    __syncthreads();   // h2n ready

    if (w == qtr) {
#pragma unroll
      for (int m = 0; m < 4; ++m)
#pragma unroll
        for (int ks = 0; ks < 4; ++ks)
          af[m][ks] = *(const s8v*)&h2n[(m * 16 + ln) * 136 + ks * 32 + q * 8];
    }
    // extraction reads h2n; next qtr's stage-2 writes are fenced by its own
    // post-stage-1 barrier -> no extra barrier needed here.
  }
  __syncthreads();   // final: extraction drained before vt overwrites h1c/h2n

  // --- prime B tile 0 while vt is being built ---
  s8v bf[4];
  tile_load(bf, Wg2, 0, lane);

  // --- build vt: vt[j][e] = v[e,j] (f32), row 32 = 1.0 ---
  // Wave w writes/reads ONLY columns [w*64, w*64+64) -> no barrier from here on.
  {
    const float* vrow = vj + (size_t)(B0 + tid) * 32;
#pragma unroll
    for (int j4 = 0; j4 < 8; ++j4) {
      float4 vv = *(const float4*)(vrow + j4 * 4);
      vt[(j4 * 4 + 0) * 260 + tid] = vv.x;
      vt[(j4 * 4 + 1) * 260 + tid] = vv.y;
      vt[(j4 * 4 + 2) * 260 + tid] = vv.z;
      vt[(j4 * 4 + 3) * 260 + tid] = vv.w;
    }
    vt[32 * 260 + tid] = 1.0f;
  }

  // --- G-loop: 66 flat tiles, depth-1 prefetch, zero barriers (r5 structure) ---
#pragma unroll 1
  for (int n = 0; n < 33; ++n) {
    tile_compute<0>(bf, vt, n, eoff, af, oa);
    tile_load(bf, Wg2, n + 1, lane);
  }
#pragma unroll 1
  for (int n = 33; n < 66; ++n) {
    tile_compute<1>(bf, vt, n - 33, eoff, af, oa);
    tile_load(bf, Wg2, n + 1, lane);   // n=65 -> tile 66 = pad overread (W2f region), unused
  }

  // --- epilogue: out[e,i] f32 ---
#pragma unroll
  for (int m = 0; m < 4; ++m)
#pragma unroll
    for (int ih = 0; ih < 2; ++ih)
#pragma unroll
      for (int r = 0; r < 4; ++r) {
        int e = B0 + w * 64 + m * 16 + q * 4 + r;
        out[(size_t)e * 32 + ih * 16 + ln] = oa[ih][m][r];
      }
}

extern "C" void kernel_launch(void* const* d_in, const int* in_sizes, int n_in,
                              void* d_out, int out_size, void* d_ws, size_t ws_size,
                              hipStream_t stream) {
  const float* pos_i = (const float*)d_in[0];
  const float* pos_j = (const float*)d_in[1];
  const float* vj    = (const float*)d_in[2];
  const float* W1    = (const float*)d_in[3];
  const float* b1    = (const float*)d_in[4];
  const float* W2    = (const float*)d_in[5];
  const float* b2    = (const float*)d_in[6];
  const float* W3    = (const float*)d_in[7];
  const float* b3    = (const float*)d_in[8];
  float* outp = (float*)d_out;

  unsigned short* Wg2 = (unsigned short*)d_ws;
  unsigned short* W2f = (unsigned short*)((char*)d_ws + 270336);
  unsigned short* b3f = (unsigned short*)((char*)d_ws + 303104);
  float*          b3c = (float*)((char*)d_ws + 305152);

  prep_pack<<<528, 256, 0, stream>>>(W2, W3, b3, Wg2, W2f, b3f, b3c);
  fnn_fused<<<NBLK, 256, 0, stream>>>(pos_i, pos_j, vj, W1, b1, b2, W2f, Wg2, b3f, b3c, outp);
}

// Round 21
// 175.644 us; speedup vs baseline: 1.3141x; 1.1218x over previous
//
#include <hip/hip_runtime.h>

// out[e,i] = sum_j mat[e,i,j] v[e,j] + bias[e,i],  [mat|bias] = MLP(pos).reshape(32,33)
// Round-22: TERMINAL — exact revert to r13, the best measured configuration
// (kernel 98.7us, bench 177.5us, VGPR 100, zero spill). r20's setprio variant
// regressed (117.8us, MfmaUtil 34->27.8): per-m-chain priority flips (528/wave)
// add scalar overhead and defeat the natural 2-wave MFMA/VALU interleave when
// both waves run the same phase pattern (m190 GEMM-null regime, not m191 attn).
// Closed arcs: occupancy caps 64/84 spill (r9/r14/r15/r16); 512-thr blocks
// quantize 2-or-4 waves (r14); split kernels >= 111us vs 98.7 fused (r17-r19);
// prefetch depth 1/2 null (r5/r6); 32x32 shape neutral-to-confounded (r10/r11);
// setprio negative (r20). Kernel is ~2.9x its 34us MFMA floor, pinned by
// allocator-imposed 2 waves/SIMD latency exposure.
// Structure: fused; prologue = W2L LDS-staged (global_load_lds once), 64-edge
// phases, 9 barriers; G-loop = barrier-free, register-B depth-1 prefetch from
// L2-resident Wg2; per-wave vt columns.
//   P[e, col] = h2[e,0:128] @ Wpack[0:128, col]   (col = j*32+i; W3-only)
//   out[e,i]  = sum_{col: i} vext[e,j] * P[e,col] + (b3 mini-GEMM)
// LDS 67584 B (prologue: h1c[64][136] @0, h2n[64][136] @17408, W2L @34816;
// G-loop: vt[33][260] @0 overlays h1c+h2n). 2 blocks/CU (reg-capped anyway).
// ws: Wg2 @0 (270336), W2f @270336 (32768), b3f @303104 (2048), b3c @305152 (128).

#define E_TOTAL 262144
#define EPB 256
#define NBLK (E_TOTAL / EPB)

typedef float f32x4 __attribute__((ext_vector_type(4)));
typedef short s8v  __attribute__((ext_vector_type(8)));
typedef unsigned int u32;

__device__ __forceinline__ unsigned short f2bf(float x) {
  unsigned u = __float_as_uint(x);
  u += 0x7fffu + ((u >> 16) & 1u);
  return (unsigned short)(u >> 16);
}

__device__ __forceinline__ void ld16_g2l(const void* g, void* l) {
  __builtin_amdgcn_global_load_lds((const __attribute__((address_space(1))) u32*)g,
                                   (__attribute__((address_space(3))) u32*)l, 16, 0, 0);
}

// ---------------- prep: pack W2/W3/b3 into MFMA B-fragment order ----------------
// Coalesced f32 reads, scattered bf16 writes (r7 version, verified).
__global__ void prep_pack(const float* __restrict__ W2, const float* __restrict__ W3,
                          const float* __restrict__ b3,
                          unsigned short* __restrict__ Wg2, unsigned short* __restrict__ W2f,
                          unsigned short* __restrict__ b3f, float* __restrict__ b3c) {
  int idx = blockIdx.x * 256 + threadIdx.x;   // 528 blocks cover 135168
  if (idx < 135168) {
    int k = idx / 1056, c = idx % 1056;
    int i = c / 33, jc = c % 33;
    int col = jc * 32 + i;                    // Wg2 col = j*32 + i
    int nnt = col >> 4, low = col & 15;
    int nn = (nnt & 1) ? (33 + (nnt >> 1)) : (nnt >> 1);   // permuted tile order
    int ks = k >> 5, kr = k & 31;
    int lane = ((kr >> 3) << 4) + low;
    int jj = k & 7;
    Wg2[((nn * 4 + ks) * 64 + lane) * 8 + jj] = f2bf(W3[idx]);
  }
  if (idx < 16384) {
    int k = idx >> 7, n = idx & 127;
    int ks = k >> 5, kr = k & 31;
    int nt = n >> 4, low = n & 15;
    int l = ((kr >> 3) << 4) + low;
    int jj = k & 7;
    W2f[((ks * 8 + nt) * 64 + l) * 8 + jj] = f2bf(W2[idx]);
  }
  if (idx < 1024) {
    int jj = idx & 7, lane = (idx >> 3) & 63, ih = idx >> 9;
    int j = ((lane >> 4) << 3) + jj, i = ih * 16 + (lane & 15);
    b3f[idx] = f2bf(b3[i * 33 + j]);
  }
  if (idx < 32) b3c[idx] = b3[idx * 33 + 32];
}

// ---------------- G-loop helpers (register-resident B, direct from L2) ----------------
__device__ __forceinline__ void tile_load(s8v (&dst)[4], const unsigned short* __restrict__ Wg2,
                                          int n, int lane) {
  const s8v* src = (const s8v*)(Wg2 + (size_t)n * 2048 + lane * 8);
#pragma unroll
  for (int ks = 0; ks < 4; ++ks) dst[ks] = src[ks * 64];
}

template <int IH>
__device__ __forceinline__ void tile_compute(const s8v (&bf)[4], const float* __restrict__ vt,
                                             int j, int eoff,
                                             const s8v (&af)[4][4], float (&oa)[2][4][4]) {
  const f32x4 zero4 = {0.f, 0.f, 0.f, 0.f};
  const float* vp = vt + j * 260 + eoff;
#pragma unroll
  for (int m = 0; m < 4; ++m) {
    f32x4 p = __builtin_amdgcn_mfma_f32_16x16x32_bf16(af[m][0], bf[0], zero4, 0, 0, 0);
#pragma unroll
    for (int ks = 1; ks < 4; ++ks)
      p = __builtin_amdgcn_mfma_f32_16x16x32_bf16(af[m][ks], bf[ks], p, 0, 0, 0);
    f32x4 vv = *(const f32x4*)(vp + m * 16);
#pragma unroll
    for (int r = 0; r < 4; ++r) oa[IH][m][r] += vv[r] * p[r];
  }
}

// ---------------- fused main kernel (r13 structure, exact) ----------------
// 256 threads (4 waves), 256 edges/block; wave w owns edges [B0+w*64, B0+w*64+64).
// LDS: prologue h1c u16[64][136] @0, h2n u16[64][136] @17408, W2L u16[16384] @34816;
//      G-loop vt f32[33][260] @0 (overlays h1c+h2n). Total 67584 B.
__global__ __launch_bounds__(256, 2) void fnn_fused(
    const float* __restrict__ pos_i, const float* __restrict__ pos_j,
    const float* __restrict__ vj, const float* __restrict__ W1,
    const float* __restrict__ b1, const float* __restrict__ b2,
    const unsigned short* __restrict__ W2f, const unsigned short* __restrict__ Wg2,
    const unsigned short* __restrict__ b3f, const float* __restrict__ b3c,
    float* __restrict__ out) {
  __shared__ __attribute__((aligned(16))) char smem[67584];
  float* vt = (float*)smem;                                  // [33][260], G-loop phase
  unsigned short* h1c = (unsigned short*)smem;               // [64][136], prologue
  unsigned short* h2n = (unsigned short*)(smem + 17408);     // [64][136], prologue
  unsigned short* W2L = (unsigned short*)(smem + 34816);     // [16384],   prologue

  const int tid = threadIdx.x;
  const int w = tid >> 6, lane = tid & 63, q = lane >> 4, ln = lane & 15;
  const int B0 = blockIdx.x * EPB;
  const int eoff = w * 64 + q * 4;

  // --- stage W2f -> LDS once (async, zero registers; drained by first barrier) ---
  {
    const unsigned short* src = W2f + tid * 8;
    char* dstb = smem + 34816 + w * 1024;   // wave-uniform base
#pragma unroll
    for (int cc = 0; cc < 8; ++cc)
      ld16_g2l(src + cc * 2048, dstb + cc * 4096);
  }

  // --- out-acc init via b3 mini-GEMM: oa[ih][m][r] = sum_j v[e,j] b3[i*33+j] + b3[i*33+32] ---
  float oa[2][4][4];
  {
    s8v av[4];
#pragma unroll
    for (int m = 0; m < 4; ++m) {
      int e = B0 + w * 64 + m * 16 + ln;
      const float4 va = *(const float4*)(vj + (size_t)e * 32 + q * 8);
      const float4 vb = *(const float4*)(vj + (size_t)e * 32 + q * 8 + 4);
      s8v t;
      t[0] = (short)f2bf(va.x); t[1] = (short)f2bf(va.y);
      t[2] = (short)f2bf(va.z); t[3] = (short)f2bf(va.w);
      t[4] = (short)f2bf(vb.x); t[5] = (short)f2bf(vb.y);
      t[6] = (short)f2bf(vb.z); t[7] = (short)f2bf(vb.w);
      av[m] = t;
    }
#pragma unroll
    for (int ih = 0; ih < 2; ++ih) {
      s8v b3fr = *(const s8v*)(b3f + (ih * 64 + lane) * 8);
      float cbv = b3c[ih * 16 + ln];
      f32x4 ci = {cbv, cbv, cbv, cbv};
#pragma unroll
      for (int m = 0; m < 4; ++m) {
        f32x4 p = __builtin_amdgcn_mfma_f32_16x16x32_bf16(av[m], b3fr, ci, 0, 0, 0);
#pragma unroll
        for (int r = 0; r < 4; ++r) oa[ih][m][r] = p[r];
      }
    }
  }

  // --- W1/b1/b2 register slices ---
  const int hh0 = (tid & 15) * 8;
  float w1r[4][8], b1r[8], b2r[8];
#pragma unroll
  for (int d = 0; d < 4; ++d)
#pragma unroll
    for (int u = 0; u < 8; ++u) w1r[d][u] = W1[d * 128 + hh0 + u];
#pragma unroll
  for (int u = 0; u < 8; ++u) b1r[u] = b1[hh0 + u];
#pragma unroll
  for (int s = 0; s < 8; ++s) b2r[s] = b2[s * 16 + ln];

  // --- stages 1+2 per quarter (64 edges/phase), 2 barriers/qtr ---
  s8v af[4][4];
  for (int qtr = 0; qtr < 4; ++qtr) {
    // stage 1: all 64 edges of this quarter; thread computes 4 edges x 8 cols
#pragma unroll
    for (int half = 0; half < 4; ++half) {
      int ee = (tid >> 4) + half * 16;
      int eg = B0 + qtr * 64 + ee;
      float2 pi = *(const float2*)(pos_i + (size_t)eg * 2);
      float2 pj = *(const float2*)(pos_j + (size_t)eg * 2);
      s8v hv;
#pragma unroll
      for (int u = 0; u < 8; ++u) {
        float o = b1r[u] + pi.x * w1r[0][u] + pi.y * w1r[1][u] +
                  pj.x * w1r[2][u] + pj.y * w1r[3][u];
        hv[u] = (short)f2bf(fmaxf(o, 0.f));
      }
      *(s8v*)&h1c[ee * 136 + hh0] = hv;
    }
    __syncthreads();   // h1c ready (also drains W2L staging on qtr 0)

    // stage 2: wave w owns tile-row mt=w (edges w*16..w*16+16), iterates 8 nt
#pragma unroll
    for (int s = 0; s < 8; ++s) {
      f32x4 a4 = {0.f, 0.f, 0.f, 0.f};
#pragma unroll
      for (int ks = 0; ks < 4; ++ks) {
        s8v afr = *(const s8v*)&h1c[(w * 16 + ln) * 136 + ks * 32 + q * 8];
        s8v bfr = *(const s8v*)&W2L[((ks * 8 + s) * 64 + lane) * 8];
        a4 = __builtin_amdgcn_mfma_f32_16x16x32_bf16(afr, bfr, a4, 0, 0, 0);
      }
      int eb = w * 16 + q * 4;
      int kc = s * 16 + ln;
#pragma unroll
      for (int r = 0; r < 4; ++r)
        h2n[(eb + r) * 136 + kc] = f2bf(fmaxf(a4[r] + b2r[s], 0.f));
    }
    __syncthreads();   // h2n ready

    if (w == qtr) {
#pragma unroll
      for (int m = 0; m < 4; ++m)
#pragma unroll
        for (int ks = 0; ks < 4; ++ks)
          af[m][ks] = *(const s8v*)&h2n[(m * 16 + ln) * 136 + ks * 32 + q * 8];
    }
    // extraction reads h2n; next qtr's stage-2 writes are fenced by its own
    // post-stage-1 barrier -> no extra barrier needed here.
  }
  __syncthreads();   // final: extraction drained before vt overwrites h1c/h2n

  // --- prime B tile 0 while vt is being built ---
  s8v bf[4];
  tile_load(bf, Wg2, 0, lane);

  // --- build vt: vt[j][e] = v[e,j] (f32), row 32 = 1.0 ---
  // Wave w writes/reads ONLY columns [w*64, w*64+64) -> no barrier from here on.
  {
    const float* vrow = vj + (size_t)(B0 + tid) * 32;
#pragma unroll
    for (int j4 = 0; j4 < 8; ++j4) {
      float4 vv = *(const float4*)(vrow + j4 * 4);
      vt[(j4 * 4 + 0) * 260 + tid] = vv.x;
      vt[(j4 * 4 + 1) * 260 + tid] = vv.y;
      vt[(j4 * 4 + 2) * 260 + tid] = vv.z;
      vt[(j4 * 4 + 3) * 260 + tid] = vv.w;
    }
    vt[32 * 260 + tid] = 1.0f;
  }

  // --- G-loop: 66 flat tiles, depth-1 prefetch, zero barriers (r5 structure) ---
#pragma unroll 1
  for (int n = 0; n < 33; ++n) {
    tile_compute<0>(bf, vt, n, eoff, af, oa);
    tile_load(bf, Wg2, n + 1, lane);
  }
#pragma unroll 1
  for (int n = 33; n < 66; ++n) {
    tile_compute<1>(bf, vt, n - 33, eoff, af, oa);
    tile_load(bf, Wg2, n + 1, lane);   // n=65 -> tile 66 = pad overread (W2f region), unused
  }

  // --- epilogue: out[e,i] f32 ---
#pragma unroll
  for (int m = 0; m < 4; ++m)
#pragma unroll
    for (int ih = 0; ih < 2; ++ih)
#pragma unroll
      for (int r = 0; r < 4; ++r) {
        int e = B0 + w * 64 + m * 16 + q * 4 + r;
        out[(size_t)e * 32 + ih * 16 + ln] = oa[ih][m][r];
      }
}

extern "C" void kernel_launch(void* const* d_in, const int* in_sizes, int n_in,
                              void* d_out, int out_size, void* d_ws, size_t ws_size,
                              hipStream_t stream) {
  const float* pos_i = (const float*)d_in[0];
  const float* pos_j = (const float*)d_in[1];
  const float* vj    = (const float*)d_in[2];
  const float* W1    = (const float*)d_in[3];
  const float* b1    = (const float*)d_in[4];
  const float* W2    = (const float*)d_in[5];
  const float* b2    = (const float*)d_in[6];
  const float* W3    = (const float*)d_in[7];
  const float* b3    = (const float*)d_in[8];
  float* outp = (float*)d_out;

  unsigned short* Wg2 = (unsigned short*)d_ws;
  unsigned short* W2f = (unsigned short*)((char*)d_ws + 270336);
  unsigned short* b3f = (unsigned short*)((char*)d_ws + 303104);
  float*          b3c = (float*)((char*)d_ws + 305152);

  prep_pack<<<528, 256, 0, stream>>>(W2, W3, b3, Wg2, W2f, b3f, b3c);
  fnn_fused<<<NBLK, 256, 0, stream>>>(pos_i, pos_j, vj, W1, b1, b2, W2f, Wg2, b3f, b3c, outp);
}